// Round 13
// baseline (1124.961 us; speedup 1.0000x reference)
//
#include <hip/hip_runtime.h>
#include <hip/hip_fp16.h>
#include <string.h>

#define PER  149796
#define NN   1048573          // 1 + 7*PER
#define HDIM 64
#define EDIM 32
#define NIOU 192
#define NS   256              // root accumulator slices

typedef _Float16 f16;
typedef _Float16 f16x8 __attribute__((ext_vector_type(8)));
typedef _Float16 f16x2 __attribute__((ext_vector_type(2)));
typedef float    f32x4 __attribute__((ext_vector_type(4)));

__device__ __forceinline__ float sigf(float x){ return 1.0f/(1.0f+__expf(-x)); }
__device__ __forceinline__ float tanh_f(float x){
  float ax = fabsf(x);
  float e  = __expf(-2.0f*ax);
  float t  = (1.0f - e)/(1.0f + e);
  return x < 0.0f ? -t : t;
}

// packed f16x2 global atomic add (fire-and-forget); device pass only.
__device__ __forceinline__ void atomAddH2(f16x2* p, f16 a, f16 b){
#if defined(__HIP_DEVICE_COMPILE__)
  typedef _Float16 h2 __attribute__((ext_vector_type(2)));
  h2 v; v[0]=a; v[1]=b;
  (void)__builtin_amdgcn_global_atomic_fadd_v2f16(
      (__attribute__((address_space(1))) h2*)p, v);
#else
  (void)p; (void)a; (void)b;
#endif
}

// ================= tables + MFMA packs (fused) =================
// B-frag order for mfma_f32_16x16x32_f16 (verified R4): lane L: n=t*16+(L&15), k=s*32+(L>>4)*8+j
__global__ __launch_bounds__(256) void tablepack_kernel(
    const float* __restrict__ emb, const float* __restrict__ Wiou, const float* __restrict__ biou,
    const float* __restrict__ Wf, const float* __restrict__ bf,
    const float* __restrict__ Uf, const float* __restrict__ Uiou,
    float* __restrict__ embWiou, float* __restrict__ embWf,
    f16* __restrict__ Bfp, f16* __restrict__ Biop)
{
  if (blockIdx.x < 1024){
    int v = blockIdx.x;
    int m = threadIdx.x;
    const float* x = emb + (size_t)v*EDIM;
    if (m < NIOU){
      float a = biou[m];
      #pragma unroll
      for (int e=0;e<EDIM;e++) a += Wiou[m*EDIM+e]*x[e];
      embWiou[(size_t)v*NIOU + m] = a;
    } else {
      int mm = m - NIOU;
      float a = bf[mm];
      #pragma unroll
      for (int e=0;e<EDIM;e++) a += Wf[mm*EDIM+e]*x[e];
      embWf[(size_t)v*HDIM + mm] = a;
    }
  } else {
    for (int i = threadIdx.x; i < 2*4*64*8; i += 256){
      int j = i & 7, L = (i>>3)&63, st = i>>9;
      int t = st & 3, s = st >> 2;
      int k = s*32 + (L>>4)*8 + j;
      int n = t*16 + (L&15);
      Bfp[i] = (f16)Uf[n*HDIM + k];
    }
    for (int i = threadIdx.x; i < 2*12*64*8; i += 256){
      int j = i & 7, L = (i>>3)&63, st = i>>9;
      int t = st % 12, s = st / 12;
      int k = s*32 + (L>>4)*8 + j;
      int n = t*16 + (L&15);
      Biop[i] = (f16)Uiou[n*HDIM + k];
    }
  }
}

// ================= per-level kernel (push, 32 nodes per wave) =================
// One 64-thread wave per 32 nodes (two 16-row MFMA tiles, acc regs reused).
// mode: 0 = leaf (no accum read, atomic out)
//       1 = mid  (accum read, atomic out)
//       2 = level1 (accum read, fused root reduction -> rootslice)
// doZero: zero own accIn rows after reading (pre-zeroes buffer for level d-2).
__global__ __launch_bounds__(64,4) void level_kernel(
    const int* __restrict__ tok, const int* __restrict__ parent,
    const float* __restrict__ embWiou, const float* __restrict__ embWf,
    const f16* __restrict__ Biopack, const f16* __restrict__ Ufpack,
    f16x2* __restrict__ accIn, f16x2* __restrict__ accOut,
    float* __restrict__ rootslice,
    int poff, int ppoff, int mode, int doZero)
{
  __shared__ f16 Ah[32*72];     // 4608 B
  __shared__ f16 FAf[32*68];    // 4352 B
  __shared__ float redH[4*64];  // 1024 B (mode 2)
  __shared__ float redF[4*64];  // 1024 B (mode 2)
  int lane = threadIdx.x;
  int j0   = blockIdx.x*32;
  int q = lane>>4, c16 = lane&15;

  // ---- phase 1: copy own accumulated child-sums (contiguous) -> LDS transpose
  if (mode != 0){
    #pragma unroll
    for (int i=0;i<32;i++){
      int j = j0 + i; if (j > PER-1) j = PER-1;
      f16x2 v = accIn[(size_t)j*HDIM + lane];
      Ah[i*72 + lane]  = v.x;
      FAf[i*68 + lane] = v.y;
    }
    if (doZero){
      int rows = PER - j0; if (rows > 32) rows = 32;
      uint4 z; z.x=0; z.y=0; z.z=0; z.w=0;
      uint4* Z = (uint4*)(accIn + (size_t)j0*HDIM);
      for (int i = lane; i < rows*16; i += 64) Z[i] = z;
    }
  } else {
    #pragma unroll
    for (int i=0;i<32;i++){
      Ah[i*72 + lane]  = (f16)0.f;
      FAf[i*68 + lane] = (f16)0.f;
    }
  }

  float sH[4] = {0.f,0.f,0.f,0.f};
  float sF[4] = {0.f,0.f,0.f,0.f};
  int tok0 = (mode == 2) ? tok[0] : 0;
  const f16x8* Bp = (const f16x8*)Biopack;
  const f16x8* Up = (const f16x8*)Ufpack;

  for (int t2=0; t2<2; ++t2){
    int base = t2*16;
    // ---- phase 2: iou MFMA + epilogue for this 16-row tile
    f16x8 A0 = *(const f16x8*)(Ah + (base+c16)*72 + q*8);
    f16x8 A1 = *(const f16x8*)(Ah + (base+c16)*72 + 32 + q*8);
    f32x4 acc[12];
    #pragma unroll
    for (int nt=0;nt<12;nt++) acc[nt] = (f32x4){0.f,0.f,0.f,0.f};
    #pragma unroll
    for (int nt=0;nt<12;nt++){
      f16x8 B0 = Bp[nt*64 + lane];
      f16x8 B1 = Bp[(12+nt)*64 + lane];
      acc[nt] = __builtin_amdgcn_mfma_f32_16x16x32_f16(A0, B0, acc[nt], 0,0,0);
      acc[nt] = __builtin_amdgcn_mfma_f32_16x16x32_f16(A1, B1, acc[nt], 0,0,0);
    }
    float cc[4][4];
    f16   hh[4][4];
    int   prow_[4]; int wt_[4]; bool ok_[4];
    #pragma unroll
    for (int r=0;r<4;r++){
      int j = j0 + base + q*4 + r;
      bool ok = j < PER;
      int jl = ok ? j : PER-1;
      int g = poff + jl;
      int tk = tok[g];
      const float* tr = embWiou + (size_t)tk*NIOU;
      ok_[r] = ok;
      if (mode != 2){
        int pg = parent[g];
        prow_[r] = pg - ppoff;
        wt_[r]   = tok[pg];
      } else {
        prow_[r] = 0;
        wt_[r]   = tok0;
      }
      int lrow = base + q*4 + r;
      #pragma unroll
      for (int nt=0;nt<4;nt++){
        int col = nt*16 + c16;
        float ai = acc[nt][r]   + tr[col];
        float ao = acc[nt+4][r] + tr[64+col];
        float au = acc[nt+8][r] + tr[128+col];
        float fav = (float)FAf[lrow*68 + col];
        float c = sigf(ai)*tanh_f(au) + fav;
        float h = sigf(ao)*tanh_f(c);
        cc[r][nt] = c;
        hh[r][nt] = (f16)h;
      }
    }
    // ---- phase 3: h -> Ah (this tile's rows, input already consumed), Uf MFMA, push
    #pragma unroll
    for (int r=0;r<4;r++)
      #pragma unroll
      for (int nt=0;nt<4;nt++)
        Ah[(base+q*4+r)*72 + nt*16 + c16] = hh[r][nt];
    f16x8 H0 = *(const f16x8*)(Ah + (base+c16)*72 + q*8);
    f16x8 H1 = *(const f16x8*)(Ah + (base+c16)*72 + 32 + q*8);
    f32x4 g4[4];
    #pragma unroll
    for (int nt=0;nt<4;nt++) g4[nt] = (f32x4){0.f,0.f,0.f,0.f};
    #pragma unroll
    for (int nt=0;nt<4;nt++){
      f16x8 B0 = Up[nt*64 + lane];
      f16x8 B1 = Up[(4+nt)*64 + lane];
      g4[nt] = __builtin_amdgcn_mfma_f32_16x16x32_f16(H0, B0, g4[nt], 0,0,0);
      g4[nt] = __builtin_amdgcn_mfma_f32_16x16x32_f16(H1, B1, g4[nt], 0,0,0);
    }
    #pragma unroll
    for (int r=0;r<4;r++){
      if (!ok_[r]) continue;
      const float* wr = embWf + (size_t)wt_[r]*HDIM;
      size_t rb = (size_t)prow_[r]*HDIM;
      #pragma unroll
      for (int nt=0;nt<4;nt++){
        int col = nt*16 + c16;
        float v = sigf(g4[nt][r] + wr[col]) * cc[r][nt];
        if (mode == 2){
          sH[nt] += (float)hh[r][nt];
          sF[nt] += v;
        } else {
          atomAddH2(&accOut[rb + col], hh[r][nt], (f16)v);
        }
      }
    }
  }

  if (mode == 2){
    // block-local reduction over q, then sliced global atomics
    #pragma unroll
    for (int nt=0;nt<4;nt++){
      redH[q*64 + nt*16 + c16] = sH[nt];
      redF[q*64 + nt*16 + c16] = sF[nt];
    }
    float tH = redH[lane] + redH[64+lane] + redH[128+lane] + redH[192+lane];
    float tF = redF[lane] + redF[64+lane] + redF[128+lane] + redF[192+lane];
    int sl = blockIdx.x & (NS-1);
    atomicAdd(&rootslice[sl*128 + 64 + lane], tH);   // h sums at [64..127]
    atomicAdd(&rootslice[sl*128 + lane],      tF);   // fc sums at [0..63]
  }
}

// ================= root cell (reduces slices inline) =================
__global__ void rootnode_kernel(
    const int* __restrict__ tok, const float* __restrict__ emb,
    const float* __restrict__ Wiou, const float* __restrict__ biou, const float* __restrict__ Uiou,
    const float* __restrict__ rootslice, float* __restrict__ out)
{
  __shared__ float hsh[64];
  int m = threadIdx.x;
  if (m >= HDIM) return;
  float fcs = 0.f, hs = 0.f;
  for (int s=0; s<NS; ++s){
    fcs += rootslice[s*128 + m];
    hs  += rootslice[s*128 + 64 + m];
  }
  hsh[m] = hs;
  __syncthreads();
  int t = tok[0];
  float ai=biou[m], ao=biou[HDIM+m], au=biou[2*HDIM+m];
  for (int e=0;e<EDIM;e++){
    float xe = emb[(size_t)t*EDIM+e];
    ai += Wiou[(size_t)m*EDIM+e]*xe;
    ao += Wiou[(size_t)(HDIM+m)*EDIM+e]*xe;
    au += Wiou[(size_t)(2*HDIM+m)*EDIM+e]*xe;
  }
  for (int k=0;k<HDIM;k++){
    float hv = hsh[k];
    ai += Uiou[(size_t)m*HDIM+k]*hv;
    ao += Uiou[(size_t)(HDIM+m)*HDIM+k]*hv;
    au += Uiou[(size_t)(2*HDIM+m)*HDIM+k]*hv;
  }
  float c = sigf(ai)*tanh_f(au) + fcs;
  out[m] = sigf(ao)*tanh_f(c);
}

// ================= launch =================
static inline char* alignup(char* p){
  uintptr_t u = (uintptr_t)p;
  u = (u + 255) & ~(uintptr_t)255;
  return (char*)u;
}

extern "C" void kernel_launch(void* const* d_in, const int* in_sizes, int n_in,
                              void* d_out, int out_size, void* d_ws, size_t ws_size,
                              hipStream_t stream)
{
  const int*   tok    = (const int*)d_in[0];
  const int*   parent = (const int*)d_in[1];
  const float* emb    = (const float*)d_in[4];
  const float* Wiou   = (const float*)d_in[5];
  const float* biou   = (const float*)d_in[6];
  const float* Uiou   = (const float*)d_in[7];
  const float* Wf     = (const float*)d_in[8];
  const float* bf     = (const float*)d_in[9];
  const float* Uf     = (const float*)d_in[10];
  float* out = (float*)d_out;

  char* w = (char*)d_ws;
  size_t BUF = (size_t)PER*HDIM*sizeof(f16x2);     // 38.3 MB, multiple of 256
  f16x2* bufA      = (f16x2*)w;  w = alignup(w + BUF);
  f16x2* bufB      = (f16x2*)w;  w = alignup(w + BUF);
  float* embWiou   = (float*)w;  w = alignup(w + 1024*NIOU*sizeof(float));
  float* embWf     = (float*)w;  w = alignup(w + 1024*HDIM*sizeof(float));
  float* rootslice = (float*)w;  w = alignup(w + (size_t)NS*128*sizeof(float));
  f16*   Ufpack    = (f16*)w;    w = alignup(w + 2*4*64*8*sizeof(f16));
  f16*   Biopack   = (f16*)w;    w = alignup(w + 2*12*64*8*sizeof(f16));

  const int NBL = (PER + 31)/32;   // 4682 blocks of 64 threads (32 nodes each)

  (void)hipMemsetAsync(bufA, 0, 2*BUF, stream);                       // A and B adjacent
  (void)hipMemsetAsync(rootslice, 0, (size_t)NS*128*sizeof(float), stream);
  tablepack_kernel<<<1025, 256, 0, stream>>>(emb, Wiou, biou, Wf, bf, Uf, Uiou,
                                             embWiou, embWf, Ufpack, Biopack);

  // d=7 leaf: mode 0, atomic into bufA
  level_kernel<<<NBL, 64, 0, stream>>>(tok, parent, embWiou, embWf, Biopack, Ufpack,
                                       bufB /*unused*/, bufA, rootslice,
                                       1 + 6*PER, 1 + 5*PER, 0, 0);
  // d=6..2: mode 1, ping-pong; zero own accIn for reuse two levels later
  f16x2* accIn = bufA; f16x2* accOut = bufB;
  for (int d=6; d>=2; --d){
    level_kernel<<<NBL, 64, 0, stream>>>(tok, parent, embWiou, embWf, Biopack, Ufpack,
                                         accIn, accOut, rootslice,
                                         1 + (d-1)*PER, 1 + (d-2)*PER, 1, (d > 2) ? 1 : 0);
    f16x2* t2 = accIn; accIn = accOut; accOut = t2;
  }
  // d=1: mode 2 — fused root reduction into rootslice
  level_kernel<<<NBL, 64, 0, stream>>>(tok, parent, embWiou, embWf, Biopack, Ufpack,
                                       accIn, accOut /*unused*/, rootslice,
                                       1, 0, 2, 0);

  rootnode_kernel<<<1, 64, 0, stream>>>(tok, emb, Wiou, biou, Uiou, rootslice, out);
}

// Round 14
// 1047.102 us; speedup vs baseline: 1.0744x; 1.0744x over previous
//
#include <hip/hip_runtime.h>
#include <hip/hip_fp16.h>
#include <string.h>

#define PER  149796
#define NN   1048573          // 1 + 7*PER
#define HDIM 64
#define EDIM 32
#define NIOU 192
#define NS   256              // root accumulator slices

typedef _Float16 f16;
typedef _Float16 f16x8 __attribute__((ext_vector_type(8)));
typedef _Float16 f16x2 __attribute__((ext_vector_type(2)));
typedef float    f32x4 __attribute__((ext_vector_type(4)));

// fast activations: v_rcp_f32 instead of precise division (1-ulp, budget 2e-2)
__device__ __forceinline__ float sigf(float x){
  return __builtin_amdgcn_rcpf(1.0f + __expf(-x));
}
__device__ __forceinline__ float tanh_f(float x){
  return 2.0f*__builtin_amdgcn_rcpf(1.0f + __expf(-2.0f*x)) - 1.0f;
}

// packed f16x2 global atomic add (fire-and-forget); device pass only.
__device__ __forceinline__ void atomAddH2(f16x2* p, f16 a, f16 b){
#if defined(__HIP_DEVICE_COMPILE__)
  typedef _Float16 h2 __attribute__((ext_vector_type(2)));
  h2 v; v[0]=a; v[1]=b;
  (void)__builtin_amdgcn_global_atomic_fadd_v2f16(
      (__attribute__((address_space(1))) h2*)p, v);
#else
  (void)p; (void)a; (void)b;
#endif
}

// ================= tables + MFMA packs (fused) =================
// B-frag order for mfma_f32_16x16x32_f16 (verified R4): lane L: n=t*16+(L&15), k=s*32+(L>>4)*8+j
__global__ __launch_bounds__(256) void tablepack_kernel(
    const float* __restrict__ emb, const float* __restrict__ Wiou, const float* __restrict__ biou,
    const float* __restrict__ Wf, const float* __restrict__ bf,
    const float* __restrict__ Uf, const float* __restrict__ Uiou,
    float* __restrict__ embWiou, float* __restrict__ embWf,
    f16* __restrict__ Bfp, f16* __restrict__ Biop)
{
  if (blockIdx.x < 1024){
    int v = blockIdx.x;
    int m = threadIdx.x;
    const float* x = emb + (size_t)v*EDIM;
    if (m < NIOU){
      float a = biou[m];
      #pragma unroll
      for (int e=0;e<EDIM;e++) a += Wiou[m*EDIM+e]*x[e];
      embWiou[(size_t)v*NIOU + m] = a;
    } else {
      int mm = m - NIOU;
      float a = bf[mm];
      #pragma unroll
      for (int e=0;e<EDIM;e++) a += Wf[mm*EDIM+e]*x[e];
      embWf[(size_t)v*HDIM + mm] = a;
    }
  } else {
    for (int i = threadIdx.x; i < 2*4*64*8; i += 256){
      int j = i & 7, L = (i>>3)&63, st = i>>9;
      int t = st & 3, s = st >> 2;
      int k = s*32 + (L>>4)*8 + j;
      int n = t*16 + (L&15);
      Bfp[i] = (f16)Uf[n*HDIM + k];
    }
    for (int i = threadIdx.x; i < 2*12*64*8; i += 256){
      int j = i & 7, L = (i>>3)&63, st = i>>9;
      int t = st % 12, s = st / 12;
      int k = s*32 + (L>>4)*8 + j;
      int n = t*16 + (L&15);
      Biop[i] = (f16)Uiou[n*HDIM + k];
    }
  }
}

// ================= per-level kernel (push; 4 independent waves/block) =================
// Each wave owns 16 nodes; no cross-wave coupling, NO __syncthreads (same-wave
// LDS dependencies are ordered by compiler-inserted lgkmcnt waits).
// mode: 0 = leaf (no accum read, no iou MFMA (A=0), atomic out)
//       1 = mid  (accum read, atomic out)
//       2 = level1 (accum read, fused root reduction -> rootslice)
__global__ __launch_bounds__(256,8) void level_kernel(
    const int* __restrict__ tok, const int* __restrict__ parent,
    const float* __restrict__ embWiou, const float* __restrict__ embWf,
    const f16* __restrict__ Biopack, const f16* __restrict__ Ufpack,
    const f16x2* __restrict__ accIn, f16x2* __restrict__ accOut,
    float* __restrict__ rootslice,
    int poff, int ppoff, int mode)
{
  __shared__ f16 AhAll[4*16*72];    // 9216 B
  __shared__ f16 FAfAll[4*16*68];   // 8704 B
  int lane = threadIdx.x & 63;
  int wv   = threadIdx.x >> 6;
  f16* Ah  = AhAll  + wv*16*72;
  f16* FAf = FAfAll + wv*16*68;
  int j0 = (blockIdx.x*4 + wv)*16;
  if (j0 >= PER) return;            // wave-uniform, no barriers in kernel
  int q = lane>>4, c16 = lane&15;

  const f16x8* Bp = (const f16x8*)Biopack;
  const f16x8* Up = (const f16x8*)Ufpack;

  f32x4 acc[12];
  #pragma unroll
  for (int nt=0;nt<12;nt++) acc[nt] = (f32x4){0.f,0.f,0.f,0.f};

  if (mode != 0){
    // phase 1: copy own accumulated child-sums (contiguous rows) -> LDS transpose
    #pragma unroll
    for (int i=0;i<16;i++){
      int j = j0 + i; if (j > PER-1) j = PER-1;
      f16x2 v = accIn[(size_t)j*HDIM + lane];
      Ah[i*72 + lane]  = v.x;
      FAf[i*68 + lane] = v.y;
    }
    f16x8 A0 = *(const f16x8*)(Ah + c16*72 + q*8);
    f16x8 A1 = *(const f16x8*)(Ah + c16*72 + 32 + q*8);
    // phase 2: iou MFMA
    #pragma unroll
    for (int nt=0;nt<12;nt++){
      f16x8 B0 = Bp[nt*64 + lane];
      f16x8 B1 = Bp[(12+nt)*64 + lane];
      acc[nt] = __builtin_amdgcn_mfma_f32_16x16x32_f16(A0, B0, acc[nt], 0,0,0);
      acc[nt] = __builtin_amdgcn_mfma_f32_16x16x32_f16(A1, B1, acc[nt], 0,0,0);
    }
  }

  int tok0 = (mode == 2) ? tok[0] : 0;
  float cc[4][4];
  f16   hh[4][4];
  int   prow_[4]; int wt_[4]; bool ok_[4];
  #pragma unroll
  for (int r=0;r<4;r++){
    int j = j0 + q*4 + r;
    bool ok = j < PER;
    int jl = ok ? j : PER-1;
    int g = poff + jl;
    int tk = tok[g];
    const float* tr = embWiou + (size_t)tk*NIOU;
    ok_[r] = ok;
    if (mode != 2){
      int pg = parent[g];
      prow_[r] = pg - ppoff;
      wt_[r]   = tok[pg];
    } else {
      prow_[r] = 0;
      wt_[r]   = tok0;
    }
    int lrow = q*4 + r;
    #pragma unroll
    for (int nt=0;nt<4;nt++){
      int col = nt*16 + c16;
      float ai = acc[nt][r]   + tr[col];
      float ao = acc[nt+4][r] + tr[64+col];
      float au = acc[nt+8][r] + tr[128+col];
      float fav = (mode != 0) ? (float)FAf[lrow*68 + col] : 0.0f;
      float c = sigf(ai)*tanh_f(au) + fav;
      float h = sigf(ao)*tanh_f(c);
      cc[r][nt] = c;
      hh[r][nt] = (f16)h;
    }
  }
  // phase 3: h -> Ah (A-layout), Uf MFMA, push {h,fc}
  #pragma unroll
  for (int r=0;r<4;r++)
    #pragma unroll
    for (int nt=0;nt<4;nt++)
      Ah[(q*4+r)*72 + nt*16 + c16] = hh[r][nt];
  f16x8 H0 = *(const f16x8*)(Ah + c16*72 + q*8);
  f16x8 H1 = *(const f16x8*)(Ah + c16*72 + 32 + q*8);
  f32x4 g4[4];
  #pragma unroll
  for (int nt=0;nt<4;nt++) g4[nt] = (f32x4){0.f,0.f,0.f,0.f};
  #pragma unroll
  for (int nt=0;nt<4;nt++){
    f16x8 B0 = Up[nt*64 + lane];
    f16x8 B1 = Up[(4+nt)*64 + lane];
    g4[nt] = __builtin_amdgcn_mfma_f32_16x16x32_f16(H0, B0, g4[nt], 0,0,0);
    g4[nt] = __builtin_amdgcn_mfma_f32_16x16x32_f16(H1, B1, g4[nt], 0,0,0);
  }
  if (mode != 2){
    #pragma unroll
    for (int r=0;r<4;r++){
      if (!ok_[r]) continue;
      const float* wr = embWf + (size_t)wt_[r]*HDIM;
      size_t rb = (size_t)prow_[r]*HDIM;
      #pragma unroll
      for (int nt=0;nt<4;nt++){
        int col = nt*16 + c16;
        float v = sigf(g4[nt][r] + wr[col]) * cc[r][nt];
        atomAddH2(&accOut[rb + col], hh[r][nt], (f16)v);
      }
    }
  } else {
    const float* wr = embWf + (size_t)tok0*HDIM;
    float sH[4] = {0.f,0.f,0.f,0.f};
    float sF[4] = {0.f,0.f,0.f,0.f};
    #pragma unroll
    for (int r=0;r<4;r++){
      if (!ok_[r]) continue;
      #pragma unroll
      for (int nt=0;nt<4;nt++){
        int col = nt*16 + c16;
        float v = sigf(g4[nt][r] + wr[col]) * cc[r][nt];
        sH[nt] += (float)hh[r][nt];
        sF[nt] += v;
      }
    }
    int sl = (blockIdx.x*4 + wv) & (NS-1);
    #pragma unroll
    for (int nt=0;nt<4;nt++){
      int col = nt*16 + c16;
      atomicAdd(&rootslice[sl*128 + col],      sF[nt]);  // fc at [0..63]
      atomicAdd(&rootslice[sl*128 + 64 + col], sH[nt]);  // h  at [64..127]
    }
  }
}

// ================= root cell (reduces slices inline) =================
__global__ void rootnode_kernel(
    const int* __restrict__ tok, const float* __restrict__ emb,
    const float* __restrict__ Wiou, const float* __restrict__ biou, const float* __restrict__ Uiou,
    const float* __restrict__ rootslice, float* __restrict__ out)
{
  __shared__ float hsh[64];
  int m = threadIdx.x;
  if (m >= HDIM) return;
  float fcs = 0.f, hs = 0.f;
  for (int s=0; s<NS; ++s){
    fcs += rootslice[s*128 + m];
    hs  += rootslice[s*128 + 64 + m];
  }
  hsh[m] = hs;
  __syncthreads();
  int t = tok[0];
  float ai=biou[m], ao=biou[HDIM+m], au=biou[2*HDIM+m];
  for (int e=0;e<EDIM;e++){
    float xe = emb[(size_t)t*EDIM+e];
    ai += Wiou[(size_t)m*EDIM+e]*xe;
    ao += Wiou[(size_t)(HDIM+m)*EDIM+e]*xe;
    au += Wiou[(size_t)(2*HDIM+m)*EDIM+e]*xe;
  }
  for (int k=0;k<HDIM;k++){
    float hv = hsh[k];
    ai += Uiou[(size_t)m*HDIM+k]*hv;
    ao += Uiou[(size_t)(HDIM+m)*HDIM+k]*hv;
    au += Uiou[(size_t)(2*HDIM+m)*HDIM+k]*hv;
  }
  float c = sigf(ai)*tanh_f(au) + fcs;
  out[m] = sigf(ao)*tanh_f(c);
}

// ================= launch =================
static inline char* alignup(char* p){
  uintptr_t u = (uintptr_t)p;
  u = (u + 255) & ~(uintptr_t)255;
  return (char*)u;
}

extern "C" void kernel_launch(void* const* d_in, const int* in_sizes, int n_in,
                              void* d_out, int out_size, void* d_ws, size_t ws_size,
                              hipStream_t stream)
{
  const int*   tok    = (const int*)d_in[0];
  const int*   parent = (const int*)d_in[1];
  const float* emb    = (const float*)d_in[4];
  const float* Wiou   = (const float*)d_in[5];
  const float* biou   = (const float*)d_in[6];
  const float* Uiou   = (const float*)d_in[7];
  const float* Wf     = (const float*)d_in[8];
  const float* bf     = (const float*)d_in[9];
  const float* Uf     = (const float*)d_in[10];
  float* out = (float*)d_out;

  char* w = (char*)d_ws;
  size_t BUF = (size_t)PER*HDIM*sizeof(f16x2);     // 38.3 MB
  f16x2* bufA      = (f16x2*)w;  w = alignup(w + BUF);
  f16x2* bufB      = (f16x2*)w;  w = alignup(w + BUF);
  float* embWiou   = (float*)w;  w = alignup(w + 1024*NIOU*sizeof(float));
  float* embWf     = (float*)w;  w = alignup(w + 1024*HDIM*sizeof(float));
  float* rootslice = (float*)w;  w = alignup(w + (size_t)NS*128*sizeof(float));
  f16*   Ufpack    = (f16*)w;    w = alignup(w + 2*4*64*8*sizeof(f16));
  f16*   Biopack   = (f16*)w;    w = alignup(w + 2*12*64*8*sizeof(f16));

  const int NB4 = (PER + 63)/64;   // 2341 blocks x 4 waves x 16 nodes

  (void)hipMemsetAsync(rootslice, 0, (size_t)NS*128*sizeof(float), stream);
  tablepack_kernel<<<1025, 256, 0, stream>>>(emb, Wiou, biou, Wf, bf, Uf, Uiou,
                                             embWiou, embWf, Ufpack, Biopack);

  // d=7 leaf: mode 0, atomic into freshly-zeroed bufA (memset also primes L2)
  (void)hipMemsetAsync(bufA, 0, BUF, stream);
  level_kernel<<<NB4, 256, 0, stream>>>(tok, parent, embWiou, embWf, Biopack, Ufpack,
                                        bufB /*unused*/, bufA, rootslice,
                                        1 + 6*PER, 1 + 5*PER, 0);
  // d=6..2: mode 1, ping-pong; memset accOut right before each (L2-warm atomics)
  f16x2* accIn = bufA; f16x2* accOut = bufB;
  for (int d=6; d>=2; --d){
    (void)hipMemsetAsync(accOut, 0, BUF, stream);
    level_kernel<<<NB4, 256, 0, stream>>>(tok, parent, embWiou, embWf, Biopack, Ufpack,
                                          accIn, accOut, rootslice,
                                          1 + (d-1)*PER, 1 + (d-2)*PER, 1);
    f16x2* t2 = accIn; accIn = accOut; accOut = t2;
  }
  // d=1: mode 2 — fused root reduction into rootslice (no accOut, no memset)
  level_kernel<<<NB4, 256, 0, stream>>>(tok, parent, embWiou, embWf, Biopack, Ufpack,
                                        accIn, accOut /*unused*/, rootslice,
                                        1, 0, 2);

  rootnode_kernel<<<1, 64, 0, stream>>>(tok, emb, Wiou, biou, Uiou, rootslice, out);
}

// Round 15
// 553.810 us; speedup vs baseline: 2.0313x; 1.8907x over previous
//
#include <hip/hip_runtime.h>
#include <hip/hip_fp16.h>
#include <string.h>

#define PER  149796
#define NN   1048573          // 1 + 7*PER
#define HDIM 64
#define EDIM 32
#define NIOU 192
#define NS   256              // root accumulator slices

typedef _Float16 f16;
typedef _Float16 f16x8 __attribute__((ext_vector_type(8)));
typedef _Float16 f16x2 __attribute__((ext_vector_type(2)));
typedef float    f32x4 __attribute__((ext_vector_type(4)));

// fast activations: v_rcp_f32 instead of precise division (~1 ulp; abs budget 2e-2)
__device__ __forceinline__ float sigf(float x){
  return __builtin_amdgcn_rcpf(1.0f + __expf(-x));
}
__device__ __forceinline__ float tanh_f(float x){
  return 2.0f*__builtin_amdgcn_rcpf(1.0f + __expf(-2.0f*x)) - 1.0f;
}

// packed f16x2 global atomic add (fire-and-forget); device pass only.
__device__ __forceinline__ void atomAddH2(f16x2* p, f16 a, f16 b){
#if defined(__HIP_DEVICE_COMPILE__)
  typedef _Float16 h2 __attribute__((ext_vector_type(2)));
  h2 v; v[0]=a; v[1]=b;
  (void)__builtin_amdgcn_global_atomic_fadd_v2f16(
      (__attribute__((address_space(1))) h2*)p, v);
#else
  (void)p; (void)a; (void)b;
#endif
}

// ================= tables + MFMA packs (fused) =================
// B-frag order for mfma_f32_16x16x32_f16 (verified R4): lane L: n=t*16+(L&15), k=s*32+(L>>4)*8+j
__global__ __launch_bounds__(256) void tablepack_kernel(
    const float* __restrict__ emb, const float* __restrict__ Wiou, const float* __restrict__ biou,
    const float* __restrict__ Wf, const float* __restrict__ bf,
    const float* __restrict__ Uf, const float* __restrict__ Uiou,
    float* __restrict__ embWiou, float* __restrict__ embWf,
    f16* __restrict__ Bfp, f16* __restrict__ Biop)
{
  if (blockIdx.x < 1024){
    int v = blockIdx.x;
    int m = threadIdx.x;
    const float* x = emb + (size_t)v*EDIM;
    if (m < NIOU){
      float a = biou[m];
      #pragma unroll
      for (int e=0;e<EDIM;e++) a += Wiou[m*EDIM+e]*x[e];
      embWiou[(size_t)v*NIOU + m] = a;
    } else {
      int mm = m - NIOU;
      float a = bf[mm];
      #pragma unroll
      for (int e=0;e<EDIM;e++) a += Wf[mm*EDIM+e]*x[e];
      embWf[(size_t)v*HDIM + mm] = a;
    }
  } else {
    for (int i = threadIdx.x; i < 2*4*64*8; i += 256){
      int j = i & 7, L = (i>>3)&63, st = i>>9;
      int t = st & 3, s = st >> 2;
      int k = s*32 + (L>>4)*8 + j;
      int n = t*16 + (L&15);
      Bfp[i] = (f16)Uf[n*HDIM + k];
    }
    for (int i = threadIdx.x; i < 2*12*64*8; i += 256){
      int j = i & 7, L = (i>>3)&63, st = i>>9;
      int t = st % 12, s = st / 12;
      int k = s*32 + (L>>4)*8 + j;
      int n = t*16 + (L&15);
      Biop[i] = (f16)Uiou[n*HDIM + k];
    }
  }
}

// ================= per-level kernel (push; R12 config: 1 wave / 16 nodes) ======
// mode: 0 = leaf (no accum read, no iou MFMA, atomic out)
//       1 = mid  (accum read, atomic out)
//       2 = level1 (accum read, fused root reduction -> rootslice)
// __launch_bounds__(64,4): VGPR cap 128 — NO spills (R14's (256,8) capped at 64
// and spilled the MFMA accumulators to scratch -> 6x HBM traffic).
__global__ __launch_bounds__(64,4) void level_kernel(
    const int* __restrict__ tok, const int* __restrict__ parent,
    const float* __restrict__ embWiou, const float* __restrict__ embWf,
    const f16* __restrict__ Biopack, const f16* __restrict__ Ufpack,
    const f16x2* __restrict__ accIn, f16x2* __restrict__ accOut,
    float* __restrict__ rootslice,
    int poff, int ppoff, int mode)
{
  __shared__ f16 Ah[16*72];     // 2304 B
  __shared__ f16 FAf[16*68];    // 2176 B
  int lane = threadIdx.x;
  int j0   = blockIdx.x*16;
  int q = lane>>4, c16 = lane&15;

  const f16x8* Bp = (const f16x8*)Biopack;
  const f16x8* Up = (const f16x8*)Ufpack;

  f32x4 acc[12];
  #pragma unroll
  for (int nt=0;nt<12;nt++) acc[nt] = (f32x4){0.f,0.f,0.f,0.f};

  if (mode != 0){
    // phase 1: own accumulated child-sums (contiguous) -> LDS transpose
    #pragma unroll
    for (int i=0;i<16;i++){
      int j = j0 + i; if (j > PER-1) j = PER-1;
      f16x2 v = accIn[(size_t)j*HDIM + lane];
      Ah[i*72 + lane]  = v.x;
      FAf[i*68 + lane] = v.y;
    }
    __syncthreads();
    f16x8 A0 = *(const f16x8*)(Ah + c16*72 + q*8);
    f16x8 A1 = *(const f16x8*)(Ah + c16*72 + 32 + q*8);
    // phase 2: iou MFMA
    #pragma unroll
    for (int nt=0;nt<12;nt++){
      f16x8 B0 = Bp[nt*64 + lane];
      f16x8 B1 = Bp[(12+nt)*64 + lane];
      acc[nt] = __builtin_amdgcn_mfma_f32_16x16x32_f16(A0, B0, acc[nt], 0,0,0);
      acc[nt] = __builtin_amdgcn_mfma_f32_16x16x32_f16(A1, B1, acc[nt], 0,0,0);
    }
  }

  int tok0 = (mode == 2) ? tok[0] : 0;
  float cc[4][4];
  f16   hh[4][4];
  int   prow_[4]; int wt_[4]; bool ok_[4];
  #pragma unroll
  for (int r=0;r<4;r++){
    int j = j0 + q*4 + r;
    bool ok = j < PER;
    int jl = ok ? j : PER-1;
    int g = poff + jl;
    int tk = tok[g];
    const float* tr = embWiou + (size_t)tk*NIOU;
    ok_[r] = ok;
    if (mode != 2){
      int pg = parent[g];
      prow_[r] = pg - ppoff;
      wt_[r]   = tok[pg];
    } else {
      prow_[r] = 0;
      wt_[r]   = tok0;
    }
    int lrow = q*4 + r;
    #pragma unroll
    for (int nt=0;nt<4;nt++){
      int col = nt*16 + c16;
      float ai = acc[nt][r]   + tr[col];
      float ao = acc[nt+4][r] + tr[64+col];
      float au = acc[nt+8][r] + tr[128+col];
      float fav = (mode != 0) ? (float)FAf[lrow*68 + col] : 0.0f;
      float c = sigf(ai)*tanh_f(au) + fav;
      float h = sigf(ao)*tanh_f(c);
      cc[r][nt] = c;
      hh[r][nt] = (f16)h;
    }
  }
  __syncthreads();
  // phase 3: h -> Ah (A-layout), Uf MFMA, push {h,fc}
  #pragma unroll
  for (int r=0;r<4;r++)
    #pragma unroll
    for (int nt=0;nt<4;nt++)
      Ah[(q*4+r)*72 + nt*16 + c16] = hh[r][nt];
  __syncthreads();
  f16x8 H0 = *(const f16x8*)(Ah + c16*72 + q*8);
  f16x8 H1 = *(const f16x8*)(Ah + c16*72 + 32 + q*8);
  f32x4 g4[4];
  #pragma unroll
  for (int nt=0;nt<4;nt++) g4[nt] = (f32x4){0.f,0.f,0.f,0.f};
  #pragma unroll
  for (int nt=0;nt<4;nt++){
    f16x8 B0 = Up[nt*64 + lane];
    f16x8 B1 = Up[(4+nt)*64 + lane];
    g4[nt] = __builtin_amdgcn_mfma_f32_16x16x32_f16(H0, B0, g4[nt], 0,0,0);
    g4[nt] = __builtin_amdgcn_mfma_f32_16x16x32_f16(H1, B1, g4[nt], 0,0,0);
  }
  if (mode != 2){
    #pragma unroll
    for (int r=0;r<4;r++){
      if (!ok_[r]) continue;
      const float* wr = embWf + (size_t)wt_[r]*HDIM;
      size_t rb = (size_t)prow_[r]*HDIM;
      #pragma unroll
      for (int nt=0;nt<4;nt++){
        int col = nt*16 + c16;
        float v = sigf(g4[nt][r] + wr[col]) * cc[r][nt];
        atomAddH2(&accOut[rb + col], hh[r][nt], (f16)v);
      }
    }
  } else {
    const float* wr = embWf + (size_t)tok0*HDIM;
    float sH[4] = {0.f,0.f,0.f,0.f};
    float sF[4] = {0.f,0.f,0.f,0.f};
    #pragma unroll
    for (int r=0;r<4;r++){
      if (!ok_[r]) continue;
      #pragma unroll
      for (int nt=0;nt<4;nt++){
        int col = nt*16 + c16;
        float v = sigf(g4[nt][r] + wr[col]) * cc[r][nt];
        sH[nt] += (float)hh[r][nt];
        sF[nt] += v;
      }
    }
    int sl = blockIdx.x & (NS-1);
    #pragma unroll
    for (int nt=0;nt<4;nt++){
      int col = nt*16 + c16;
      atomicAdd(&rootslice[sl*128 + col],      sF[nt]);  // fc at [0..63]
      atomicAdd(&rootslice[sl*128 + 64 + col], sH[nt]);  // h  at [64..127]
    }
  }
}

// ================= root cell (reduces slices inline) =================
__global__ void rootnode_kernel(
    const int* __restrict__ tok, const float* __restrict__ emb,
    const float* __restrict__ Wiou, const float* __restrict__ biou, const float* __restrict__ Uiou,
    const float* __restrict__ rootslice, float* __restrict__ out)
{
  __shared__ float hsh[64];
  int m = threadIdx.x;
  if (m >= HDIM) return;
  float fcs = 0.f, hs = 0.f;
  for (int s=0; s<NS; ++s){
    fcs += rootslice[s*128 + m];
    hs  += rootslice[s*128 + 64 + m];
  }
  hsh[m] = hs;
  __syncthreads();
  int t = tok[0];
  float ai=biou[m], ao=biou[HDIM+m], au=biou[2*HDIM+m];
  for (int e=0;e<EDIM;e++){
    float xe = emb[(size_t)t*EDIM+e];
    ai += Wiou[(size_t)m*EDIM+e]*xe;
    ao += Wiou[(size_t)(HDIM+m)*EDIM+e]*xe;
    au += Wiou[(size_t)(2*HDIM+m)*EDIM+e]*xe;
  }
  for (int k=0;k<HDIM;k++){
    float hv = hsh[k];
    ai += Uiou[(size_t)m*HDIM+k]*hv;
    ao += Uiou[(size_t)(HDIM+m)*HDIM+k]*hv;
    au += Uiou[(size_t)(2*HDIM+m)*HDIM+k]*hv;
  }
  float c = sigf(ai)*tanh_f(au) + fcs;
  out[m] = sigf(ao)*tanh_f(c);
}

// ================= launch =================
static inline char* alignup(char* p){
  uintptr_t u = (uintptr_t)p;
  u = (u + 255) & ~(uintptr_t)255;
  return (char*)u;
}

extern "C" void kernel_launch(void* const* d_in, const int* in_sizes, int n_in,
                              void* d_out, int out_size, void* d_ws, size_t ws_size,
                              hipStream_t stream)
{
  const int*   tok    = (const int*)d_in[0];
  const int*   parent = (const int*)d_in[1];
  const float* emb    = (const float*)d_in[4];
  const float* Wiou   = (const float*)d_in[5];
  const float* biou   = (const float*)d_in[6];
  const float* Uiou   = (const float*)d_in[7];
  const float* Wf     = (const float*)d_in[8];
  const float* bf     = (const float*)d_in[9];
  const float* Uf     = (const float*)d_in[10];
  float* out = (float*)d_out;

  char* w = (char*)d_ws;
  size_t BUF = (size_t)PER*HDIM*sizeof(f16x2);     // 38.3 MB
  f16x2* bufA      = (f16x2*)w;  w = alignup(w + BUF);
  f16x2* bufB      = (f16x2*)w;  w = alignup(w + BUF);
  float* embWiou   = (float*)w;  w = alignup(w + 1024*NIOU*sizeof(float));
  float* embWf     = (float*)w;  w = alignup(w + 1024*HDIM*sizeof(float));
  float* rootslice = (float*)w;  w = alignup(w + (size_t)NS*128*sizeof(float));
  f16*   Ufpack    = (f16*)w;    w = alignup(w + 2*4*64*8*sizeof(f16));
  f16*   Biopack   = (f16*)w;    w = alignup(w + 2*12*64*8*sizeof(f16));

  const int NB = (PER + 15)/16;   // 9363 blocks of 64 threads (R12 config)

  (void)hipMemsetAsync(rootslice, 0, (size_t)NS*128*sizeof(float), stream);
  tablepack_kernel<<<1025, 256, 0, stream>>>(emb, Wiou, biou, Wf, bf, Uf, Uiou,
                                             embWiou, embWf, Ufpack, Biopack);

  // d=7 leaf: mode 0, atomic into freshly-zeroed bufA (memset also primes L2)
  (void)hipMemsetAsync(bufA, 0, BUF, stream);
  level_kernel<<<NB, 64, 0, stream>>>(tok, parent, embWiou, embWf, Biopack, Ufpack,
                                      bufB /*unused*/, bufA, rootslice,
                                      1 + 6*PER, 1 + 5*PER, 0);
  // d=6..2: mode 1, ping-pong; memset accOut right before each (L2-warm atomics)
  f16x2* accIn = bufA; f16x2* accOut = bufB;
  for (int d=6; d>=2; --d){
    (void)hipMemsetAsync(accOut, 0, BUF, stream);
    level_kernel<<<NB, 64, 0, stream>>>(tok, parent, embWiou, embWf, Biopack, Ufpack,
                                        accIn, accOut, rootslice,
                                        1 + (d-1)*PER, 1 + (d-2)*PER, 1);
    f16x2* t2 = accIn; accIn = accOut; accOut = t2;
  }
  // d=1: mode 2 — fused root reduction into rootslice (no accOut, no memset)
  level_kernel<<<NB, 64, 0, stream>>>(tok, parent, embWiou, embWf, Biopack, Ufpack,
                                      accIn, accOut /*unused*/, rootslice,
                                      1, 0, 2);

  rootnode_kernel<<<1, 64, 0, stream>>>(tok, emb, Wiou, biou, Uiou, rootslice, out);
}